// Round 5
// baseline (2599.385 us; speedup 1.0000x reference)
//
#include <hip/hip_runtime.h>
#include <math.h>

#define TOKENS  16384
#define HIDDEN  4096
#define NEXPERT 256
#define NGROUP  8
#define GSIZE   32
#define TOPKG   4
#define TOPK    8
#define RSCALE  2.5f

// One fused kernel: block = 64 tokens x ALL 256 experts, full K, routing in
// epilogue. Round-7/8: revert round-6's scalar-A experiment (global s_loads in
// the k-loop stalled on L2 latency: VALUBusy 32%, 760us). Back to LDS A+B with
// the round-0 8x8 micro-tile, but at 2 waves/EU (launch_bounds(256,2) +
// waves_per_eu(2,2), 2 blocks/CU). Model (validated on rounds 0/2): LDS cost
// is per-INSTRUCTION (~12cy/ds_read_b128 on the CU LDS pipe), so per k-step
// LDS/FMA cycle ratio = 3W(r+c) / (W*r*c/2); 8x4 = 2.25x (537us measured ~=
// 490 model), 8x8 = 1.5x -> ~330us, reachable only with >=2 waves/SIMD to
// hide ds_read latency (round-0 had 1 wave/SIMD: latency-bound at 685us).
// 8x8 is the minimum ratio at grid=256 (bigger tiles shrink the grid below
// 256 blocks). VGPR: round-0 compiled to 184 < 256 budget at wpe(2,2), no
// spill. fp32 ascending-k fmaf chain per logit BIT-IDENTICAL to rounds 0/2.
// Round 8 = identical resubmit of round 7 (infra container failure, same
// signature as round 4's flake; round-0 geometry already HW-verified).
#define BM  64
#define BK  16
#define LDA 68    // A-tile leading pad: staging writes / frag reads 2-way aliased (free)
#define LDB 260   // B-tile leading pad

__device__ __forceinline__ float sigmoid_acc(float x) {
    return 1.0f / (1.0f + expf(-x));   // accurate expf: top-k order must match ref
}

__global__ __launch_bounds__(256, 2) __attribute__((amdgpu_waves_per_eu(2, 2)))
void moe_gate_fused(const float* __restrict__ A,      // [TOKENS, HIDDEN]
                    const float* __restrict__ B,      // [NEXPERT, HIDDEN]
                    const float* __restrict__ bias,   // [NEXPERT]
                    float* __restrict__ out_idx,
                    float* __restrict__ out_w,
                    float* __restrict__ out_logits)
{
    __shared__ float As[2][BK * LDA];          // As[k][m], 64 rows
    __shared__ float Bs[2][BK * LDB];          // Bs[k][n], 256 rows
    __shared__ float gsum[BM][NGROUP + 1];

    const int tid = threadIdx.x;
    const int m0  = blockIdx.x * BM;

    // ---- staging map: thread owns (row ar, k-quad kq) ----
    // A: 64x16 tile, 1 float4/thread. B: 256x16 tile, 4 float4/thread
    // (rows p*64+ar). Global loads: 4 consecutive lanes read 64B of one row.
    const int ar = tid >> 2;     // 0..63
    const int kq = tid & 3;      // 0..3
    const float* Ag = A + (long)(m0 + ar) * HIDDEN + kq * 4;
    const float* Bg = B + (long)ar * HIDDEN + kq * 4;

    // ---- compute map: 8x32 thread grid, 8x8 micro-tile ----
    // rows row0..row0+7; cols c0..c0+3 and 128+c0..128+c0+3 (split halves so
    // B-fragment ds_read_b128 lane-addresses stride 16B -> conflict-free).
    const int tr   = tid >> 5;   // 0..7
    const int tc   = tid & 31;   // 0..31
    const int row0 = tr * 8;
    const int c0   = tc * 4;

    float4 pa, pb0, pb1, pb2, pb3;

    // prefetch tile 0
    pa  = *(const float4*)(Ag);
    pb0 = *(const float4*)(Bg + (long)0 * 64 * HIDDEN);
    pb1 = *(const float4*)(Bg + (long)1 * 64 * HIDDEN);
    pb2 = *(const float4*)(Bg + (long)2 * 64 * HIDDEN);
    pb3 = *(const float4*)(Bg + (long)3 * 64 * HIDDEN);

    // stage tile 0 -> buffer 0
    {
        float* as = As[0];
        as[(kq * 4 + 0) * LDA + ar] = pa.x;
        as[(kq * 4 + 1) * LDA + ar] = pa.y;
        as[(kq * 4 + 2) * LDA + ar] = pa.z;
        as[(kq * 4 + 3) * LDA + ar] = pa.w;
        float* bs = Bs[0];
        float vb[4][4] = {{pb0.x,pb0.y,pb0.z,pb0.w},{pb1.x,pb1.y,pb1.z,pb1.w},
                          {pb2.x,pb2.y,pb2.z,pb2.w},{pb3.x,pb3.y,pb3.z,pb3.w}};
        #pragma unroll
        for (int p = 0; p < 4; ++p)
            #pragma unroll
            for (int j = 0; j < 4; ++j)
                bs[(kq * 4 + j) * LDB + p * 64 + ar] = vb[p][j];
    }
    __syncthreads();

    float acc[8][8] = {};

    const int NKT = HIDDEN / BK;   // 256
    for (int kt = 0; kt < NKT; ++kt) {
        const int cur = kt & 1;

        if (kt + 1 < NKT) {
            const int ko = (kt + 1) * BK;
            pa  = *(const float4*)(Ag + ko);
            pb0 = *(const float4*)(Bg + (long)0 * 64 * HIDDEN + ko);
            pb1 = *(const float4*)(Bg + (long)1 * 64 * HIDDEN + ko);
            pb2 = *(const float4*)(Bg + (long)2 * 64 * HIDDEN + ko);
            pb3 = *(const float4*)(Bg + (long)3 * 64 * HIDDEN + ko);
        }

        const float* as = As[cur];
        const float* bs = Bs[cur];
        #pragma unroll
        for (int k = 0; k < BK; ++k) {
            float4 a0 = *(const float4*)(as + k * LDA + row0);       // 32-lane bcast
            float4 a1 = *(const float4*)(as + k * LDA + row0 + 4);
            float4 b0 = *(const float4*)(bs + k * LDB + c0);         // conflict-free
            float4 b1 = *(const float4*)(bs + k * LDB + 128 + c0);
            float av[8] = {a0.x, a0.y, a0.z, a0.w, a1.x, a1.y, a1.z, a1.w};
            float bv[8] = {b0.x, b0.y, b0.z, b0.w, b1.x, b1.y, b1.z, b1.w};
            #pragma unroll
            for (int i = 0; i < 8; ++i)
                #pragma unroll
                for (int j = 0; j < 8; ++j)
                    acc[i][j] = fmaf(av[i], bv[j], acc[i][j]);
        }

        if (kt + 1 < NKT) {
            float* as_w = As[cur ^ 1];
            as_w[(kq * 4 + 0) * LDA + ar] = pa.x;
            as_w[(kq * 4 + 1) * LDA + ar] = pa.y;
            as_w[(kq * 4 + 2) * LDA + ar] = pa.z;
            as_w[(kq * 4 + 3) * LDA + ar] = pa.w;
            float* bs_w = Bs[cur ^ 1];
            float vb[4][4] = {{pb0.x,pb0.y,pb0.z,pb0.w},{pb1.x,pb1.y,pb1.z,pb1.w},
                              {pb2.x,pb2.y,pb2.z,pb2.w},{pb3.x,pb3.y,pb3.z,pb3.w}};
            #pragma unroll
            for (int p = 0; p < 4; ++p)
                #pragma unroll
                for (int j = 0; j < 4; ++j)
                    bs_w[(kq * 4 + j) * LDB + p * 64 + ar] = vb[p][j];
        }
        __syncthreads();
    }

    // ---- epilogue: write logits (coalesced float4) ----
    #pragma unroll
    for (int i = 0; i < 8; ++i) {
        long row = m0 + row0 + i;
        *(float4*)(out_logits + row * NEXPERT + c0)       = make_float4(acc[i][0], acc[i][1], acc[i][2], acc[i][3]);
        *(float4*)(out_logits + row * NEXPERT + 128 + c0) = make_float4(acc[i][4], acc[i][5], acc[i][6], acc[i][7]);
    }
    __syncthreads();   // barrier drains vmcnt -> this block's logits visible via its L2

    // ---- routing phase A: per (token, group) top-2 of sigmoid(logit)+bias ----
    for (int task = tid; task < BM * NGROUP; task += 256) {
        const int tt = task >> 3;
        const int g  = task & 7;
        const float* lg = out_logits + (long)(m0 + tt) * NEXPERT + g * GSIZE;
        const float* bp = bias + g * GSIZE;
        float m1 = -INFINITY, m2 = -INFINITY;
        #pragma unroll
        for (int j4 = 0; j4 < GSIZE / 4; ++j4) {
            float4 l = *(const float4*)(lg + j4 * 4);
            float4 b = *(const float4*)(bp + j4 * 4);
            float vv[4] = {sigmoid_acc(l.x) + b.x, sigmoid_acc(l.y) + b.y,
                           sigmoid_acc(l.z) + b.z, sigmoid_acc(l.w) + b.w};
            #pragma unroll
            for (int c = 0; c < 4; ++c) {
                float x = vv[c];
                if (x > m1) { m2 = m1; m1 = x; }
                else if (x > m2) { m2 = x; }
            }
        }
        gsum[tt][g] = m1 + m2;
    }
    __syncthreads();

    // ---- routing phase B: one worker per token ----
    if (tid < BM) {
        const long tok = m0 + tid;
        const float* lg = out_logits + tok * NEXPERT;

        float gs[NGROUP];
        #pragma unroll
        for (int g = 0; g < NGROUP; ++g) gs[g] = gsum[tid][g];

        unsigned selmask = 0;
        #pragma unroll
        for (int r = 0; r < TOPKG; ++r) {
            float best = -INFINITY; int bi = 0;
            #pragma unroll
            for (int g = 0; g < NGROUP; ++g) {
                bool taken = (selmask >> g) & 1u;
                if (!taken && gs[g] > best) { best = gs[g]; bi = g; }
            }
            selmask |= 1u << bi;
        }

        float rv[TOPK]; int ri[TOPK];
        #pragma unroll
        for (int k = 0; k < TOPK; ++k) { rv[k] = -INFINITY; ri[k] = 0; }

        for (int g = 0; g < NGROUP; ++g) {
            if (!((selmask >> g) & 1u)) continue;
            #pragma unroll 4
            for (int j = 0; j < GSIZE; ++j) {
                int e = g * GSIZE + j;
                float v = sigmoid_acc(lg[e]) + bias[e];
                if (v > rv[TOPK - 1]) {
                    rv[TOPK - 1] = v; ri[TOPK - 1] = e;
                    #pragma unroll
                    for (int q = TOPK - 1; q > 0; --q) {
                        if (rv[q] > rv[q - 1]) {
                            float tv = rv[q]; rv[q] = rv[q - 1]; rv[q - 1] = tv;
                            int   ti = ri[q]; ri[q] = ri[q - 1]; ri[q - 1] = ti;
                        }
                    }
                }
            }
        }

        float pv[TOPK]; float sum = 0.0f;
        #pragma unroll
        for (int k = 0; k < TOPK; ++k) { pv[k] = rv[k] - bias[ri[k]]; sum += pv[k]; }
        float denom = sum + 1e-20f;

        #pragma unroll
        for (int k = 0; k < TOPK; ++k) {
            out_idx[tok * TOPK + k] = (float)ri[k];
            out_w[tok * TOPK + k]   = pv[k] / denom * RSCALE;
        }
    }
}

// ---------------- launch ----------------
extern "C" void kernel_launch(void* const* d_in, const int* in_sizes, int n_in,
                              void* d_out, int out_size, void* d_ws, size_t ws_size,
                              hipStream_t stream) {
    const float* hidden = (const float*)d_in[0];
    const float* gate_w = (const float*)d_in[1];
    const float* bias   = (const float*)d_in[2];

    float* out = (float*)d_out;
    float* out_idx    = out;
    float* out_w      = out + (long)TOKENS * TOPK;
    float* out_logits = out + (long)TOKENS * TOPK * 2;

    moe_gate_fused<<<TOKENS / BM, 256, 0, stream>>>(
        hidden, gate_w, bias, out_idx, out_w, out_logits);
}

// Round 6
// 756.331 us; speedup vs baseline: 3.4368x; 3.4368x over previous
//
#include <hip/hip_runtime.h>
#include <math.h>

#define TOKENS  16384
#define HIDDEN  4096
#define NEXPERT 256
#define NGROUP  8
#define GSIZE   32
#define TOPKG   4
#define TOPK    8
#define RSCALE  2.5f

// One fused kernel: block = 64 tokens x ALL 256 experts, full K, routing in
// epilogue. Round-9: A moves OFF the LDS pipe onto the VALU pipe.
// History: grid is pinned at 256 blocks (=1 block/CU) by the fused routing,
// so only 512-thr blocks reach 2 waves/EU (round-5: 256-thr + min-2-waves
// promise -> allocator cap 128 VGPR -> acc spill, WRITE_SIZE 6.5GB, 2.5ms).
// At 512 thr, outputs/thread is pinned at 32 -> micro-tile 8x4 -> LDS-instr
// ratio 6(r+c)/rc = 2.25 -> round-2's 537us IS the all-LDS floor (model 490).
// Fix: A-fragments are wave-uniform; distribute them across lanes (lane l
// holds A[row0+(l&7)][2*(l>>3)+{0,1}], ONE float2 global load per kt,
// reg-double-buffered, A out of LDS entirely) and broadcast at use with
// v_readlane -> SGPR (compile-time lane index; v_fmac v,s,v legal, 1:4 vs
// FMA). Per kt/wave: LDS 48->16 reads (B only, contiguous, conflict-free);
// VALU +128 readlanes. Model: LDS 1790cy/CU/kt < VALU 2680cy/SIMD/kt ->
// VALU-bound ~315us. fp32 ascending-k fmaf chain per logit BIT-IDENTICAL
// (same values, same order); routing untouched.
#define BM   64
#define BK   16
#define LDB  260   // B-tile leading pad
#define NTHR 512

__device__ __forceinline__ float sigmoid_acc(float x) {
    return 1.0f / (1.0f + expf(-x));   // accurate expf: top-k order must match ref
}

__device__ __forceinline__ float readlane_f(float v, int l) {
    return __int_as_float(__builtin_amdgcn_readlane(__float_as_int(v), l));
}

__global__ __launch_bounds__(NTHR, 2) __attribute__((amdgpu_waves_per_eu(2, 2)))
void moe_gate_fused(const float* __restrict__ A,      // [TOKENS, HIDDEN]
                    const float* __restrict__ B,      // [NEXPERT, HIDDEN]
                    const float* __restrict__ bias,   // [NEXPERT]
                    float* __restrict__ out_idx,
                    float* __restrict__ out_w,
                    float* __restrict__ out_logits)
{
    __shared__ float Bs[2][BK * LDB];          // Bs[k][n], 256 rows
    __shared__ float gsum[BM][NGROUP + 1];

    const int tid = threadIdx.x;
    const int m0  = blockIdx.x * BM;

    // ---- B staging map (512 threads): 256x16 tile = 1024 float4 ----
    // 2 float4/thread (8 contiguous floats of one row; 2 lanes per 64B).
    const int ar_b = tid >> 1;          // 0..255 B row
    const int q0   = (tid & 1) * 2;     // k-quad pair {0,1} or {2,3}
    const float* Bg = B + (long)ar_b * HIDDEN + q0 * 4;

    // ---- compute map: 8 waves x 64 lanes, 8x4 micro-tile ----
    // Wave w owns token rows w*8..w*8+7; lane tc owns expert cols tc*4..+3
    // (contiguous 1KiB ds_read_b128 line per wave, conflict-free).
    const int tr   = tid >> 6;   // wave 0..7
    const int tc   = tid & 63;
    const int row0 = tr * 8;
    const int c0   = tc * 4;

    // ---- A lane-distributed load map ----
    // lane l of wave w holds A[row0+(l&7)][kt*16 + 2*(l>>3) + {0,1}] as float2.
    // 8 rows x 64B per wave-load, reg double-buffered; A never touches LDS.
    const int lane = tid & 63;
    const int arow = row0 + (lane & 7);
    const int kp   = lane >> 3;          // k-pair 0..7
    const float* Ag = A + (long)(m0 + arow) * HIDDEN + kp * 2;

    float2 qa, qan;
    float4 pb0, pb1;

    // prefetch tile 0
    qa  = *(const float2*)(Ag);
    pb0 = *(const float4*)(Bg);
    pb1 = *(const float4*)(Bg + 4);

    // stage B tile 0 -> buffer 0
    {
        float* bs = Bs[0];
        bs[(q0 * 4 + 0) * LDB + ar_b] = pb0.x;
        bs[(q0 * 4 + 1) * LDB + ar_b] = pb0.y;
        bs[(q0 * 4 + 2) * LDB + ar_b] = pb0.z;
        bs[(q0 * 4 + 3) * LDB + ar_b] = pb0.w;
        bs[(q0 * 4 + 4) * LDB + ar_b] = pb1.x;
        bs[(q0 * 4 + 5) * LDB + ar_b] = pb1.y;
        bs[(q0 * 4 + 6) * LDB + ar_b] = pb1.z;
        bs[(q0 * 4 + 7) * LDB + ar_b] = pb1.w;
    }
    __syncthreads();

    float acc[8][4] = {};

    const int NKT = HIDDEN / BK;   // 256
    for (int kt = 0; kt < NKT; ++kt) {
        const int cur = kt & 1;

        if (kt + 1 < NKT) {
            const int ko = (kt + 1) * BK;
            qan = *(const float2*)(Ag + ko);
            pb0 = *(const float4*)(Bg + ko);
            pb1 = *(const float4*)(Bg + ko + 4);
        }

        const float* bs = Bs[cur];
        #pragma unroll
        for (int k = 0; k < BK; ++k) {
            float4 b0 = *(const float4*)(bs + k * LDB + c0);  // conflict-free
            #pragma unroll
            for (int i = 0; i < 8; ++i) {
                // lane (k>>1)*8 + i holds A[row0+i][kt*16 + k] in qa.{x,y}
                const int sl = (k >> 1) * 8 + i;
                const float a = (k & 1) ? readlane_f(qa.y, sl)
                                        : readlane_f(qa.x, sl);
                acc[i][0] = fmaf(a, b0.x, acc[i][0]);
                acc[i][1] = fmaf(a, b0.y, acc[i][1]);
                acc[i][2] = fmaf(a, b0.z, acc[i][2]);
                acc[i][3] = fmaf(a, b0.w, acc[i][3]);
            }
        }

        if (kt + 1 < NKT) {
            float* bs_w = Bs[cur ^ 1];
            bs_w[(q0 * 4 + 0) * LDB + ar_b] = pb0.x;
            bs_w[(q0 * 4 + 1) * LDB + ar_b] = pb0.y;
            bs_w[(q0 * 4 + 2) * LDB + ar_b] = pb0.z;
            bs_w[(q0 * 4 + 3) * LDB + ar_b] = pb0.w;
            bs_w[(q0 * 4 + 4) * LDB + ar_b] = pb1.x;
            bs_w[(q0 * 4 + 5) * LDB + ar_b] = pb1.y;
            bs_w[(q0 * 4 + 6) * LDB + ar_b] = pb1.z;
            bs_w[(q0 * 4 + 7) * LDB + ar_b] = pb1.w;
        }
        __syncthreads();
        qa = qan;
    }

    // ---- epilogue: write logits (coalesced float4) ----
    #pragma unroll
    for (int i = 0; i < 8; ++i) {
        long row = m0 + row0 + i;
        *(float4*)(out_logits + row * NEXPERT + c0) =
            make_float4(acc[i][0], acc[i][1], acc[i][2], acc[i][3]);
    }
    __syncthreads();   // barrier drains vmcnt -> this block's logits visible via its L2

    // ---- routing phase A: per (token, group) top-2 of sigmoid(logit)+bias ----
    for (int task = tid; task < BM * NGROUP; task += NTHR) {
        const int tt = task >> 3;
        const int g  = task & 7;
        const float* lg = out_logits + (long)(m0 + tt) * NEXPERT + g * GSIZE;
        const float* bp = bias + g * GSIZE;
        float m1 = -INFINITY, m2 = -INFINITY;
        #pragma unroll
        for (int j4 = 0; j4 < GSIZE / 4; ++j4) {
            float4 l = *(const float4*)(lg + j4 * 4);
            float4 b = *(const float4*)(bp + j4 * 4);
            float vv[4] = {sigmoid_acc(l.x) + b.x, sigmoid_acc(l.y) + b.y,
                           sigmoid_acc(l.z) + b.z, sigmoid_acc(l.w) + b.w};
            #pragma unroll
            for (int c = 0; c < 4; ++c) {
                float x = vv[c];
                if (x > m1) { m2 = m1; m1 = x; }
                else if (x > m2) { m2 = x; }
            }
        }
        gsum[tt][g] = m1 + m2;
    }
    __syncthreads();

    // ---- routing phase B: one worker per token ----
    if (tid < BM) {
        const long tok = m0 + tid;
        const float* lg = out_logits + tok * NEXPERT;

        float gs[NGROUP];
        #pragma unroll
        for (int g = 0; g < NGROUP; ++g) gs[g] = gsum[tid][g];

        unsigned selmask = 0;
        #pragma unroll
        for (int r = 0; r < TOPKG; ++r) {
            float best = -INFINITY; int bi = 0;
            #pragma unroll
            for (int g = 0; g < NGROUP; ++g) {
                bool taken = (selmask >> g) & 1u;
                if (!taken && gs[g] > best) { best = gs[g]; bi = g; }
            }
            selmask |= 1u << bi;
        }

        float rv[TOPK]; int ri[TOPK];
        #pragma unroll
        for (int k = 0; k < TOPK; ++k) { rv[k] = -INFINITY; ri[k] = 0; }

        for (int g = 0; g < NGROUP; ++g) {
            if (!((selmask >> g) & 1u)) continue;
            #pragma unroll 4
            for (int j = 0; j < GSIZE; ++j) {
                int e = g * GSIZE + j;
                float v = sigmoid_acc(lg[e]) + bias[e];
                if (v > rv[TOPK - 1]) {
                    rv[TOPK - 1] = v; ri[TOPK - 1] = e;
                    #pragma unroll
                    for (int q = TOPK - 1; q > 0; --q) {
                        if (rv[q] > rv[q - 1]) {
                            float tv = rv[q]; rv[q] = rv[q - 1]; rv[q - 1] = tv;
                            int   ti = ri[q]; ri[q] = ri[q - 1]; ri[q - 1] = ti;
                        }
                    }
                }
            }
        }

        float pv[TOPK]; float sum = 0.0f;
        #pragma unroll
        for (int k = 0; k < TOPK; ++k) { pv[k] = rv[k] - bias[ri[k]]; sum += pv[k]; }
        float denom = sum + 1e-20f;

        #pragma unroll
        for (int k = 0; k < TOPK; ++k) {
            out_idx[tok * TOPK + k] = (float)ri[k];
            out_w[tok * TOPK + k]   = pv[k] / denom * RSCALE;
        }
    }
}

// ---------------- launch ----------------
extern "C" void kernel_launch(void* const* d_in, const int* in_sizes, int n_in,
                              void* d_out, int out_size, void* d_ws, size_t ws_size,
                              hipStream_t stream) {
    const float* hidden = (const float*)d_in[0];
    const float* gate_w = (const float*)d_in[1];
    const float* bias   = (const float*)d_in[2];

    float* out = (float*)d_out;
    float* out_idx    = out;
    float* out_w      = out + (long)TOKENS * TOPK;
    float* out_logits = out + (long)TOKENS * TOPK * 2;

    moe_gate_fused<<<TOKENS / BM, NTHR, 0, stream>>>(
        hidden, gate_w, bias, out_idx, out_w, out_logits);
}